// Round 4
// baseline (275.641 us; speedup 1.0000x reference)
//
#include <hip/hip_runtime.h>

#define IMG_H 2048
#define IMG_W 2048
#define NIMG 4
#define NXCD 8

#define NBLK_INT (NIMG * (IMG_H / 2) * (IMG_W / 4) / 256)  // 8192 interior blocks
#define PER_IMG  (1024 + 2044)                             // 3068 border tiles per image
#define NBORDER  (NIMG * PER_IMG)                          // 12272 border tiles
#define NBLK_BOR ((NBORDER + 255) / 256)                   // 48 border blocks

__device__ __forceinline__ int refl(int i, int n) {
    i = (i < 0) ? -i : i;
    return (i >= n) ? (2 * n - 2 - i) : i;
}

__device__ __forceinline__ float clamp01(float v) {
    return fminf(fmaxf(v, 0.0f), 1.0f);
}

// 13-tap Malvar-He-Cutler demosaic at one pixel, phase (pr,pc) = (r&1, c&1).
// pr/pc are compile-time constants at all call sites -> dead cfas eliminated.
__device__ __forceinline__ void px_rgb(
    float x0,
    float xl, float xr, float xll, float xrr,      // row r: c-1, c+1, c-2, c+2
    float xu, float xd, float xuu, float xdd,      // col c: r-1, r+1, r-2, r+2
    float dul, float dur, float ddl, float ddr,    // diagonals
    int pr, int pc,
    float& R, float& G, float& B)
{
    float h1 = xl + xr, v1 = xu + xd;
    float h2 = xll + xrr, v2 = xuu + xdd;
    float diag = dul + dur + ddl + ddr;
    float cfa0 = 0.125f * (4.0f * x0 + 2.0f * (h1 + v1) - (h2 + v2));
    float cfa1 = 0.125f * (5.0f * x0 + 4.0f * h1 - h2 + 0.5f * v2 - diag);
    float cfa2 = 0.125f * (5.0f * x0 + 4.0f * v1 - v2 + 0.5f * h2 - diag);
    float cfa3 = 0.125f * (6.0f * x0 + 2.0f * diag - 1.5f * (h2 + v2));

    if (pr == 0) {
        if (pc == 0) { R = x0;   G = cfa0; B = cfa3; }
        else         { R = cfa1; G = x0;   B = cfa2; }
    } else {
        if (pc == 0) { R = cfa2; G = x0;   B = cfa1; }
        else         { R = cfa3; G = cfa0; B = x0;   }
    }
    R = clamp01(R); G = clamp01(G); B = clamp01(B);
}

// R4 (= R3 resubmit after container failure): single merged kernel.
//  - nt stores REVERTED (R2: +9us -- nt bypasses L2/L3 write buffering; default
//    policy was already optimal for the 201 MB write-once stream).
//  - XCD swizzle KEPT (R2 isolated it as ~0 cost; mechanistically sound; 3 SALU).
//  - Border work merged in as a block-uniform branch: the old separate border
//    dispatch (192 waves) serialized after interior with the GPU ~idle; merged
//    blocks overlap with interior for free. Border loops are #pragma unroll 1
//    so the scalar/refl path cannot inflate the interior path's VGPR budget.
//  - Stores grouped by plane (R,R,G,G,B,B) for DRAM page locality.
__global__ __launch_bounds__(256) void demosaic(
    const float* __restrict__ x, float* __restrict__ out)
{
    const size_t plane = (size_t)IMG_H * IMG_W;
    int bid = blockIdx.x;

    if (bid < NBLK_INT) {
        // ---------------- interior path ----------------
        // bijective (8192 % 8 == 0): XCD k owns logical blocks [k*1024,(k+1)*1024)
        int nb  = (bid & (NXCD - 1)) * (NBLK_INT / NXCD) + (bid >> 3);
        int idx = nb * 256 + (int)threadIdx.x;

        int c4   = idx & 511;           // IMG_W/4 = 512 col groups
        int rest = idx >> 9;
        int rp   = rest & 1023;         // IMG_H/2 = 1024 row pairs
        int n    = rest >> 10;
        if (rp == 0 || rp == 1023 || c4 == 0 || c4 == 511) return;  // border tiles
        int r = rp << 1;
        int c = c4 << 2;

        const float* p = x + (size_t)n * IMG_H * IMG_W;
        size_t ob = (size_t)n * 3 * plane + (size_t)r * IMG_W + c;

        const float* b = p + (size_t)r * IMG_W + c;
        float4 m2  = *(const float4*)(b - 2 * IMG_W);
        float4 m1l = *(const float4*)(b - IMG_W - 4);
        float4 m1c = *(const float4*)(b - IMG_W);
        float4 m1r = *(const float4*)(b - IMG_W + 4);
        float4 z0l = *(const float4*)(b - 4);
        float4 z0c = *(const float4*)(b);
        float4 z0r = *(const float4*)(b + 4);
        float4 z1l = *(const float4*)(b + IMG_W - 4);
        float4 z1c = *(const float4*)(b + IMG_W);
        float4 z1r = *(const float4*)(b + IMG_W + 4);
        float4 z2l = *(const float4*)(b + 2 * IMG_W - 4);
        float4 z2c = *(const float4*)(b + 2 * IMG_W);
        float4 z2r = *(const float4*)(b + 2 * IMG_W + 4);
        float4 p3  = *(const float4*)(b + 3 * IMG_W);

        float wm2[4] = {m2.x, m2.y, m2.z, m2.w};                                 // r-2: c..c+3
        float wm1[6] = {m1l.w, m1c.x, m1c.y, m1c.z, m1c.w, m1r.x};               // r-1: c-1..c+4
        float w0[8]  = {z0l.z, z0l.w, z0c.x, z0c.y, z0c.z, z0c.w, z0r.x, z0r.y}; // r:   c-2..c+5
        float w1[8]  = {z1l.z, z1l.w, z1c.x, z1c.y, z1c.z, z1c.w, z1r.x, z1r.y}; // r+1: c-2..c+5
        float w2[6]  = {z2l.w, z2c.x, z2c.y, z2c.z, z2c.w, z2r.x};               // r+2: c-1..c+4
        float w3[4]  = {p3.x, p3.y, p3.z, p3.w};                                 // r+3: c..c+3

        float R0[4], G0[4], B0[4], R1[4], G1[4], B1[4];
        #pragma unroll
        for (int j = 0; j < 4; j++) {
            // pixel (r, c+j): pr=0
            px_rgb(w0[j + 2],
                   w0[j + 1], w0[j + 3], w0[j], w0[j + 4],
                   wm1[j + 1], w1[j + 2], wm2[j], w2[j + 1],
                   wm1[j], wm1[j + 2], w1[j + 1], w1[j + 3],
                   0, j & 1, R0[j], G0[j], B0[j]);
            // pixel (r+1, c+j): pr=1
            px_rgb(w1[j + 2],
                   w1[j + 1], w1[j + 3], w1[j], w1[j + 4],
                   w0[j + 2], w2[j + 1], wm1[j + 1], w3[j],
                   w0[j + 1], w0[j + 3], w2[j], w2[j + 2],
                   1, j & 1, R1[j], G1[j], B1[j]);
        }

        // stores grouped by plane for DRAM page locality
        *(float4*)(out + ob)                     = make_float4(R0[0], R0[1], R0[2], R0[3]);
        *(float4*)(out + ob + IMG_W)             = make_float4(R1[0], R1[1], R1[2], R1[3]);
        *(float4*)(out + ob + plane)             = make_float4(G0[0], G0[1], G0[2], G0[3]);
        *(float4*)(out + ob + plane + IMG_W)     = make_float4(G1[0], G1[1], G1[2], G1[3]);
        *(float4*)(out + ob + 2 * plane)         = make_float4(B0[0], B0[1], B0[2], B0[3]);
        *(float4*)(out + ob + 2 * plane + IMG_W) = make_float4(B1[0], B1[1], B1[2], B1[3]);
    } else {
        // ---------------- border path (block-uniform branch) ----------------
        int idx = (bid - NBLK_INT) * 256 + (int)threadIdx.x;
        if (idx >= NBORDER) return;
        int n = idx / PER_IMG;
        int t = idx - n * PER_IMG;
        int rp, c4;
        if (t < 1024) { rp = (t >> 9) * 1023; c4 = t & 511; }
        else          { int j = t - 1024; rp = 1 + (j >> 1); c4 = (j & 1) * 511; }
        int r = rp << 1;
        int c = c4 << 2;

        const float* p = x + (size_t)n * IMG_H * IMG_W;
        size_t ob = (size_t)n * 3 * plane + (size_t)r * IMG_W + c;

        // unroll 1: keep this path register-light so it cannot degrade the
        // interior path's occupancy (one shared allocation per kernel).
        #pragma unroll 1
        for (int i = 0; i < 2; i++) {
            int rr = r + i;                        // r even -> pr == i
            int rm1 = refl(rr - 1, IMG_H), rm2 = refl(rr - 2, IMG_H);
            int rp1 = refl(rr + 1, IMG_H), rp2 = refl(rr + 2, IMG_H);
            const float* p0r  = p + (size_t)rr  * IMG_W;
            const float* pm1r = p + (size_t)rm1 * IMG_W;
            const float* pm2r = p + (size_t)rm2 * IMG_W;
            const float* pp1r = p + (size_t)rp1 * IMG_W;
            const float* pp2r = p + (size_t)rp2 * IMG_W;
            #pragma unroll 1
            for (int j = 0; j < 4; j++) {
                int cc  = c + j;
                int cm1 = refl(cc - 1, IMG_W), cm2 = refl(cc - 2, IMG_W);
                int cp1 = refl(cc + 1, IMG_W), cp2 = refl(cc + 2, IMG_W);
                float R, G, B;
                if (i == 0)
                    px_rgb(p0r[cc],
                           p0r[cm1], p0r[cp1], p0r[cm2], p0r[cp2],
                           pm1r[cc], pp1r[cc], pm2r[cc], pp2r[cc],
                           pm1r[cm1], pm1r[cp1], pp1r[cm1], pp1r[cp1],
                           0, cc & 1, R, G, B);
                else
                    px_rgb(p0r[cc],
                           p0r[cm1], p0r[cp1], p0r[cm2], p0r[cp2],
                           pm1r[cc], pp1r[cc], pm2r[cc], pp2r[cc],
                           pm1r[cm1], pm1r[cp1], pp1r[cm1], pp1r[cp1],
                           1, cc & 1, R, G, B);
                size_t o = ob + (size_t)i * IMG_W + j;
                out[o]             = R;
                out[o + plane]     = G;
                out[o + 2 * plane] = B;
            }
        }
    }
}

extern "C" void kernel_launch(void* const* d_in, const int* in_sizes, int n_in,
                              void* d_out, int out_size, void* d_ws, size_t ws_size,
                              hipStream_t stream) {
    const float* x = (const float*)d_in[0];
    float* out = (float*)d_out;

    // Single dispatch: 8192 interior blocks + 48 border blocks, fully overlapped.
    demosaic<<<dim3(NBLK_INT + NBLK_BOR), dim3(256), 0, stream>>>(x, out);
}

// Round 5
// 265.240 us; speedup vs baseline: 1.0392x; 1.0392x over previous
//
#include <hip/hip_runtime.h>

#define IMG_H 2048
#define IMG_W 2048
#define NIMG 4

#define NBLK_INT (NIMG * (IMG_H / 2) * (IMG_W / 4) / 256)  // 8192 interior blocks
#define PER_IMG  (1024 + 2044)                             // 3068 border tiles per image
#define NBORDER  (NIMG * PER_IMG)                          // 12272 border tiles
#define NBLK_BOR ((NBORDER + 255) / 256)                   // 48 border blocks

__device__ __forceinline__ int refl(int i, int n) {
    i = (i < 0) ? -i : i;
    return (i >= n) ? (2 * n - 2 - i) : i;
}

__device__ __forceinline__ float clamp01(float v) {
    return fminf(fmaxf(v, 0.0f), 1.0f);
}

// 13-tap Malvar-He-Cutler demosaic at one pixel, phase (pr,pc) = (r&1, c&1).
// pr/pc are compile-time constants at all call sites -> dead cfas eliminated.
__device__ __forceinline__ void px_rgb(
    float x0,
    float xl, float xr, float xll, float xrr,      // row r: c-1, c+1, c-2, c+2
    float xu, float xd, float xuu, float xdd,      // col c: r-1, r+1, r-2, r+2
    float dul, float dur, float ddl, float ddr,    // diagonals
    int pr, int pc,
    float& R, float& G, float& B)
{
    float h1 = xl + xr, v1 = xu + xd;
    float h2 = xll + xrr, v2 = xuu + xdd;
    float diag = dul + dur + ddl + ddr;
    float cfa0 = 0.125f * (4.0f * x0 + 2.0f * (h1 + v1) - (h2 + v2));
    float cfa1 = 0.125f * (5.0f * x0 + 4.0f * h1 - h2 + 0.5f * v2 - diag);
    float cfa2 = 0.125f * (5.0f * x0 + 4.0f * v1 - v2 + 0.5f * h2 - diag);
    float cfa3 = 0.125f * (6.0f * x0 + 2.0f * diag - 1.5f * (h2 + v2));

    if (pr == 0) {
        if (pc == 0) { R = x0;   G = cfa0; B = cfa3; }
        else         { R = cfa1; G = x0;   B = cfa2; }
    } else {
        if (pc == 0) { R = cfa2; G = x0;   B = cfa1; }
        else         { R = cfa3; G = cfa0; B = x0;   }
    }
    R = clamp01(R); G = clamp01(G); B = clamp01(B);
}

// R5: exact R0 configuration (identity block map -- NO XCD swizzle, which
// R2/R4 showed costs ~+6-9us by breaking DRAM page locality on the dominant
// 201MB write stream; NO nt stores; R0's interleaved store order) with ONE
// isolated change vs R0: the border work is merged into this dispatch as a
// block-uniform branch, removing the serialized 192-wave border dispatch.
// Border loops are unroll 1 so the refl/scalar path can't inflate the
// shared VGPR allocation that governs interior occupancy.
__global__ __launch_bounds__(256) void demosaic(
    const float* __restrict__ x, float* __restrict__ out)
{
    const size_t plane = (size_t)IMG_H * IMG_W;
    int bid = blockIdx.x;

    if (bid < NBLK_INT) {
        // ---------------- interior path (identical to R0 baseline) ----------------
        int idx = bid * 256 + (int)threadIdx.x;

        int c4   = idx & 511;           // IMG_W/4 = 512 col groups
        int rest = idx >> 9;
        int rp   = rest & 1023;         // IMG_H/2 = 1024 row pairs
        int n    = rest >> 10;
        if (rp == 0 || rp == 1023 || c4 == 0 || c4 == 511) return;  // border tiles
        int r = rp << 1;
        int c = c4 << 2;

        const float* p = x + (size_t)n * IMG_H * IMG_W;
        size_t ob = (size_t)n * 3 * plane + (size_t)r * IMG_W + c;

        const float* b = p + (size_t)r * IMG_W + c;
        float4 m2  = *(const float4*)(b - 2 * IMG_W);
        float4 m1l = *(const float4*)(b - IMG_W - 4);
        float4 m1c = *(const float4*)(b - IMG_W);
        float4 m1r = *(const float4*)(b - IMG_W + 4);
        float4 z0l = *(const float4*)(b - 4);
        float4 z0c = *(const float4*)(b);
        float4 z0r = *(const float4*)(b + 4);
        float4 z1l = *(const float4*)(b + IMG_W - 4);
        float4 z1c = *(const float4*)(b + IMG_W);
        float4 z1r = *(const float4*)(b + IMG_W + 4);
        float4 z2l = *(const float4*)(b + 2 * IMG_W - 4);
        float4 z2c = *(const float4*)(b + 2 * IMG_W);
        float4 z2r = *(const float4*)(b + 2 * IMG_W + 4);
        float4 p3  = *(const float4*)(b + 3 * IMG_W);

        float wm2[4] = {m2.x, m2.y, m2.z, m2.w};                                 // r-2: c..c+3
        float wm1[6] = {m1l.w, m1c.x, m1c.y, m1c.z, m1c.w, m1r.x};               // r-1: c-1..c+4
        float w0[8]  = {z0l.z, z0l.w, z0c.x, z0c.y, z0c.z, z0c.w, z0r.x, z0r.y}; // r:   c-2..c+5
        float w1[8]  = {z1l.z, z1l.w, z1c.x, z1c.y, z1c.z, z1c.w, z1r.x, z1r.y}; // r+1: c-2..c+5
        float w2[6]  = {z2l.w, z2c.x, z2c.y, z2c.z, z2c.w, z2r.x};               // r+2: c-1..c+4
        float w3[4]  = {p3.x, p3.y, p3.z, p3.w};                                 // r+3: c..c+3

        float R0[4], G0[4], B0[4], R1[4], G1[4], B1[4];
        #pragma unroll
        for (int j = 0; j < 4; j++) {
            // pixel (r, c+j): pr=0
            px_rgb(w0[j + 2],
                   w0[j + 1], w0[j + 3], w0[j], w0[j + 4],
                   wm1[j + 1], w1[j + 2], wm2[j], w2[j + 1],
                   wm1[j], wm1[j + 2], w1[j + 1], w1[j + 3],
                   0, j & 1, R0[j], G0[j], B0[j]);
            // pixel (r+1, c+j): pr=1
            px_rgb(w1[j + 2],
                   w1[j + 1], w1[j + 3], w1[j], w1[j + 4],
                   w0[j + 2], w2[j + 1], wm1[j + 1], w3[j],
                   w0[j + 1], w0[j + 3], w2[j], w2[j + 2],
                   1, j & 1, R1[j], G1[j], B1[j]);
        }

        // store order exactly as R0 baseline (best measured: 261.1us)
        *(float4*)(out + ob)                     = make_float4(R0[0], R0[1], R0[2], R0[3]);
        *(float4*)(out + ob + plane)             = make_float4(G0[0], G0[1], G0[2], G0[3]);
        *(float4*)(out + ob + 2 * plane)         = make_float4(B0[0], B0[1], B0[2], B0[3]);
        *(float4*)(out + ob + IMG_W)             = make_float4(R1[0], R1[1], R1[2], R1[3]);
        *(float4*)(out + ob + IMG_W + plane)     = make_float4(G1[0], G1[1], G1[2], G1[3]);
        *(float4*)(out + ob + IMG_W + 2 * plane) = make_float4(B1[0], B1[1], B1[2], B1[3]);
    } else {
        // ---------------- border path (block-uniform branch) ----------------
        int idx = (bid - NBLK_INT) * 256 + (int)threadIdx.x;
        if (idx >= NBORDER) return;
        int n = idx / PER_IMG;
        int t = idx - n * PER_IMG;
        int rp, c4;
        if (t < 1024) { rp = (t >> 9) * 1023; c4 = t & 511; }
        else          { int j = t - 1024; rp = 1 + (j >> 1); c4 = (j & 1) * 511; }
        int r = rp << 1;
        int c = c4 << 2;

        const float* p = x + (size_t)n * IMG_H * IMG_W;
        size_t ob = (size_t)n * 3 * plane + (size_t)r * IMG_W + c;

        // unroll 1: keep this path register-light so it cannot degrade the
        // interior path's occupancy (one shared allocation per kernel).
        #pragma unroll 1
        for (int i = 0; i < 2; i++) {
            int rr = r + i;                        // r even -> pr == i
            int rm1 = refl(rr - 1, IMG_H), rm2 = refl(rr - 2, IMG_H);
            int rp1 = refl(rr + 1, IMG_H), rp2 = refl(rr + 2, IMG_H);
            const float* p0r  = p + (size_t)rr  * IMG_W;
            const float* pm1r = p + (size_t)rm1 * IMG_W;
            const float* pm2r = p + (size_t)rm2 * IMG_W;
            const float* pp1r = p + (size_t)rp1 * IMG_W;
            const float* pp2r = p + (size_t)rp2 * IMG_W;
            #pragma unroll 1
            for (int j = 0; j < 4; j++) {
                int cc  = c + j;
                int cm1 = refl(cc - 1, IMG_W), cm2 = refl(cc - 2, IMG_W);
                int cp1 = refl(cc + 1, IMG_W), cp2 = refl(cc + 2, IMG_W);
                float R, G, B;
                if (i == 0)
                    px_rgb(p0r[cc],
                           p0r[cm1], p0r[cp1], p0r[cm2], p0r[cp2],
                           pm1r[cc], pp1r[cc], pm2r[cc], pp2r[cc],
                           pm1r[cm1], pm1r[cp1], pp1r[cm1], pp1r[cp1],
                           0, cc & 1, R, G, B);
                else
                    px_rgb(p0r[cc],
                           p0r[cm1], p0r[cp1], p0r[cm2], p0r[cp2],
                           pm1r[cc], pp1r[cc], pm2r[cc], pp2r[cc],
                           pm1r[cm1], pm1r[cp1], pp1r[cm1], pp1r[cp1],
                           1, cc & 1, R, G, B);
                size_t o = ob + (size_t)i * IMG_W + j;
                out[o]             = R;
                out[o + plane]     = G;
                out[o + 2 * plane] = B;
            }
        }
    }
}

extern "C" void kernel_launch(void* const* d_in, const int* in_sizes, int n_in,
                              void* d_out, int out_size, void* d_ws, size_t ws_size,
                              hipStream_t stream) {
    const float* x = (const float*)d_in[0];
    float* out = (float*)d_out;

    // Single dispatch: 8192 interior blocks + 48 border blocks, fully overlapped.
    demosaic<<<dim3(NBLK_INT + NBLK_BOR), dim3(256), 0, stream>>>(x, out);
}